// Round 12
// baseline (89.188 us; speedup 1.0000x reference)
//
#include <hip/hip_runtime.h>

#define LOG2E 1.4426950408889634f

// DPP: CTRL=0x00/0x55/0xAA/0xFF = quad_perm broadcast lane 0/1/2/3 of quad;
// CTRL=0x114 = row_shr:4 (lane i <- lane i-4 within 16-lane row; low 4 -> 0).
// Keep old=0 (R9-proven form).
template<int CTRL>
__device__ __forceinline__ float dppf(float v) {
    int r = __builtin_amdgcn_update_dpp(0, __float_as_int(v), CTRL, 0xF, 0xF, true);
    return __int_as_float(r);
}

// async global->LDS DMA, 4 B per lane (64 contiguous dwords per instruction)
__device__ __forceinline__ void gload_lds(const float* g, float* l) {
    __builtin_amdgcn_global_load_lds(
        (const __attribute__((address_space(1))) void*)g,
        (__attribute__((address_space(3))) void*)l, 4, 0, 0);
}

struct LaneW {
    // Gate pre-activations pre-scaled by msc = (g-lane ? -2L : -L) so that
    // r = rcp(1+exp2(z)) gives sigma(y) on sigma lanes and sigma(2y) on g lane.
    float vb, v0, v1, v2, v3;   // msc * (bias, V[0..3][g])
    float wcx;                  // L1: msc*W1[g] (x-input); L2: unused (0 path)
    float uc;                   // msc*U[g]   (own-h recurrent)
    float wc2;                  // L2: msc*W2[g] (h1 input); L1: 0
    float fw, fb;
    bool isl2;
};

// One fused call, h-materialized form. L1 lanes (quads 0,2) process step tau;
// L2 lanes (quads 1,3) process step tau-2 (2-call lag; hx = h1(tau-2) arrives
// via row_shr:4 of the previous call's entry-h). C = 2L*c.
// Zero state (h=0, C=0, hx=0, zv*=0) is exact.
__device__ __forceinline__ float lstm_step3(
    float a0, float a1, float a2, float a3, float xv,
    const LaneW& w, float& C, float& h, float& hx,
    float& zv1, float& zv2)
{
    float nhx = dppf<0x114>(h);              // entry h -> hx for NEXT call
    float zv = fmaf(a3, w.v3, fmaf(a2, w.v2, fmaf(a1, w.v1, fmaf(a0, w.v0, w.vb))));
    float zb = w.isl2 ? zv2 : fmaf(xv, w.wcx, zv);  // L2: 2-call-delayed dot
    zv2 = zv1; zv1 = zv;
    float zc = fmaf(w.wc2, hx, zb);          // cross-layer term (L1: wc2=0)
    float z  = fmaf(w.uc, h, zc);            // own recurrent term
    float e  = __builtin_amdgcn_exp2f(z);
    float r  = __builtin_amdgcn_rcpf(1.0f + e);
    float d3 = dppf<0x55>(r);                // f
    float d2 = dppf<0xAA>(r);                // sigma_g (tanh encoded)
    float d1 = dppf<0x00>(r);                // i
    float vo = dppf<0xFF>(r);                // o
    float t1 = d3 * C;
    float t2 = fmaf(4.0f * LOG2E, d2, -2.0f * LOG2E);   // = 2L*g
    C        = fmaf(d1, t2, t1);             // C = 2L*c
    float E2 = __builtin_amdgcn_exp2f(-C);   // neg = free src modifier
    float r2 = __builtin_amdgcn_rcpf(1.0f + E2);
    float tm = fmaf(2.0f, r2, -1.0f);        // tanh(c)
    h  = vo * tm;
    hx = nhx;
    return fmaf(h, w.fw, w.fb);
}

__global__ __launch_bounds__(256, 4) void pew_lstm_kernel(
    const float* __restrict__ input,
    const float* __restrict__ W1, const float* __restrict__ U1,
    const float* __restrict__ V1, const float* __restrict__ b1,
    const float* __restrict__ W2, const float* __restrict__ U2,
    const float* __restrict__ V2, const float* __restrict__ b2,
    const float* __restrict__ fcW, const float* __restrict__ fcb,
    float* __restrict__ out, int B)
{
    // per-wave staging: [wave][dbuf][704 dw] = 22528 B/block.
    // 704 = 11 DMA instructions x 64 dw — the DMA WRITES all 704 dwords
    // (pad-lane sources are clamped, but the LDS write still happens), so the
    // buffer MUST be 704, not 648. (R10/R11 bug: 648 -> cross-buffer overflow.)
    // Data row stride 81 dw -> group g reads bank 17g mod 32: conflict-free.
    __shared__ float lds[4][2][704];

    const int lane  = threadIdx.x & 63;
    const int wslot = threadIdx.x >> 6;
    const int gw    = blockIdx.x * 4 + wslot;  // global wave id
    const int chunk = gw & 7;                  // 8 time chunks per sequence
    const int seq0  = (gw >> 3) << 3;          // 8 sequences per wave
    const int grp   = lane >> 3;
    const int seq   = seq0 + grp;
    if (seq >= B) return;
    const bool isl2 = (lane & 4) != 0;
    const int  g    = lane & 3;

    LaneW w;
    w.isl2 = isl2;
    const float* Wx = isl2 ? W2 : W1;
    const float* Ux = isl2 ? U2 : U1;
    const float* Vx = isl2 ? V2 : V1;
    const float* bx = isl2 ? b2 : b1;
    const bool istanh = (g == 2);
    const float msc = istanh ? (-2.0f * LOG2E) : (-LOG2E);
    w.wcx = msc * Wx[g]; w.uc = msc * Ux[g]; w.vb = msc * bx[g];
    w.v0 = msc * Vx[g]; w.v1 = msc * Vx[4 + g];
    w.v2 = msc * Vx[8 + g]; w.v3 = msc * Vx[12 + g];
    w.wc2 = isl2 ? w.wcx : 0.0f;
    w.fw = fcW[0]; w.fb = fcb[0];

    // chunk geometry: outputs [s0, s0+128); warmup 64 steps (chunk 0: none)
    const int s0  = chunk << 7;
    const int Wm  = chunk ? 64 : 0;
    const int t0  = s0 - Wm;                   // multiple of 16
    const int nsb = (Wm + 128) >> 4;           // superblocks of 16 calls: 8 / 12
    const int sbflush = chunk ? 5 : 1;

    // per-lane global byte offsets for the 11-instruction DMA pattern:
    // LDS linear dw L = 64*i + lane maps to row r = L/81, col d = L-81r;
    // d==80 / L>=648 are pad slots (source clamped to 0, data unused).
    int off11[11];
#pragma unroll
    for (int i = 0; i < 11; i++) {
        int L = 64 * i + lane;
        int r = L / 81;
        int d = L - 81 * r;
        off11[i] = (L < 648 && d < 80) ? (r * 20480 + d * 4) : 0;
    }

    const char* __restrict__ gseq = (const char*)input + (size_t)seq0 * 20480;
    float* lbuf0 = &lds[wslot][0][0];
    float* lbuf1 = &lds[wslot][1][0];
    const int rowbase = grp * 81;              // padded row stride

    float* __restrict__ opf = out + (size_t)seq * 1024;
    const bool stlane = (lane & 7) == 4;       // one L2 lane per group stores

    // prologue: DMA superblock 0 into buf0
    {
        const char* gsb = gseq + (size_t)t0 * 20;
#pragma unroll
        for (int i = 0; i < 11; i++)
            gload_lds((const float*)(gsb + off11[i]), lbuf0 + i * 64);
    }

    float C = 0.f, h = 0.f, hx = 0.f, zv1 = 0.f, zv2 = 0.f;
    float ro[16];                              // output ring, flush 16 at a time

#pragma unroll 1
    for (int sb = 0; sb < nsb; sb++) {
        float* cb = (sb & 1) ? lbuf1 : lbuf0;
        float* nb = (sb & 1) ? lbuf0 : lbuf1;
        if (sb + 1 < nsb) {
            const char* gsb = gseq + (size_t)(t0 + 16 * (sb + 1)) * 20;
#pragma unroll
            for (int i = 0; i < 11; i++)
                gload_lds((const float*)(gsb + off11[i]), nb + i * 64);
            // wait for CURRENT buffer's 11 loads; keep next 11 in flight
            asm volatile("s_waitcnt vmcnt(11)" ::: "memory");
        } else {
            asm volatile("s_waitcnt vmcnt(0)" ::: "memory");
        }
        __builtin_amdgcn_sched_barrier(0);
        const float* mrow = cb + rowbase;
#pragma unroll
        for (int jj = 0; jj < 16; jj++) {
            float a0 = mrow[5*jj+0], a1 = mrow[5*jj+1], a2 = mrow[5*jj+2];
            float a3 = mrow[5*jj+3], xv = mrow[5*jj+4];
            float res = lstm_step3(a0, a1, a2, a3, xv,
                                   w, C, h, hx, zv1, zv2);
            if (jj >= 2) ro[jj - 2] = res; else ro[14 + jj] = res;
            if (jj == 1 && sb >= sbflush && stlane) {
                float4* op4 = (float4*)(opf + (t0 + 16 * sb - 16));
                op4[0] = make_float4(ro[0],  ro[1],  ro[2],  ro[3]);
                op4[1] = make_float4(ro[4],  ro[5],  ro[6],  ro[7]);
                op4[2] = make_float4(ro[8],  ro[9],  ro[10], ro[11]);
                op4[3] = make_float4(ro[12], ro[13], ro[14], ro[15]);
            }
        }
    }
    // drain: 2 zero-input calls finish L2 steps s0+126, s0+127, then flush
    {
        float res = lstm_step3(0.f, 0.f, 0.f, 0.f, 0.f, w, C, h, hx, zv1, zv2);
        ro[14] = res;
        res = lstm_step3(0.f, 0.f, 0.f, 0.f, 0.f, w, C, h, hx, zv1, zv2);
        ro[15] = res;
        if (stlane) {
            float4* op4 = (float4*)(opf + (s0 + 112));
            op4[0] = make_float4(ro[0],  ro[1],  ro[2],  ro[3]);
            op4[1] = make_float4(ro[4],  ro[5],  ro[6],  ro[7]);
            op4[2] = make_float4(ro[8],  ro[9],  ro[10], ro[11]);
            op4[3] = make_float4(ro[12], ro[13], ro[14], ro[15]);
        }
    }
}

extern "C" void kernel_launch(void* const* d_in, const int* in_sizes, int n_in,
                              void* d_out, int out_size, void* d_ws, size_t ws_size,
                              hipStream_t stream) {
    const float* input = (const float*)d_in[0];
    const float* W1 = (const float*)d_in[1];
    const float* U1 = (const float*)d_in[2];
    const float* V1 = (const float*)d_in[3];
    const float* b1 = (const float*)d_in[4];
    const float* W2 = (const float*)d_in[5];
    const float* U2 = (const float*)d_in[6];
    const float* V2 = (const float*)d_in[7];
    const float* b2 = (const float*)d_in[8];
    const float* fcW = (const float*)d_in[9];
    const float* fcb = (const float*)d_in[10];
    float* out = (float*)d_out;

    int B = in_sizes[0] / (1024 * 5);
    // 8 chunks per sequence, 8 seqs per wave, 4 waves per block -> B waves
    int blocks = (B + 3) / 4;
    hipLaunchKernelGGL(pew_lstm_kernel, dim3(blocks), dim3(256), 0, stream,
                       input, W1, U1, V1, b1, W2, U2, V2, b2, fcW, fcb, out, B);
}

// Round 13
// 62.177 us; speedup vs baseline: 1.4344x; 1.4344x over previous
//
#include <hip/hip_runtime.h>

#define LOG2E 1.4426950408889634f

// compile-time component pick from a float4 buffer (I is constant after unroll)
#define AV(B, I) ((I) % 4 == 0 ? (B)[(I)/4].x : (I) % 4 == 1 ? (B)[(I)/4].y \
                 : (I) % 4 == 2 ? (B)[(I)/4].z : (B)[(I)/4].w)

struct SW {
    // per-gate pre-scaled weights (uniform -> SGPR). Gate k scale:
    // k==2 (g): -2*LOG2E, else -LOG2E, so sigma = rcp(1+exp2(z)) directly and
    // g's r = sigma(2x) encodes tanh. Cell tracked as C = -2L*c.
    float b1[4], W1[4], U1[4], V1[16];
    float b2[4], W2[4], U2[4], V2[16];
    float fw, fb;
};

__device__ __forceinline__ float sigm(float z) {      // z pre-scaled by -L
    return __builtin_amdgcn_rcpf(1.0f + __builtin_amdgcn_exp2f(z));
}

// One full fused step for one sequence on one lane (both layers + FC).
__device__ __forceinline__ float fstep(
    float a0, float a1, float a2, float a3, float xx,
    const SW& s, float& h1, float& C1, float& h2, float& C2)
{
    float z1[4];
#pragma unroll
    for (int k = 0; k < 4; k++) {
        float z = s.b1[k];
        z = fmaf(a0, s.V1[k],      z);
        z = fmaf(a1, s.V1[4 + k],  z);
        z = fmaf(a2, s.V1[8 + k],  z);
        z = fmaf(a3, s.V1[12 + k], z);
        z = fmaf(xx, s.W1[k], z);
        z = fmaf(h1, s.U1[k], z);
        z1[k] = z;
    }
    float i1 = sigm(z1[0]);
    float f1 = sigm(z1[1]);
    float rg1 = sigm(z1[2]);                            // sigma(2*zg)
    float gp1 = fmaf(-4.0f * LOG2E, rg1, 2.0f * LOG2E); // -2L*tanh(zg)
    float o1 = sigm(z1[3]);
    C1 = fmaf(f1, C1, i1 * gp1);                        // C1 = -2L*c1
    float th1 = fmaf(2.0f, sigm(C1), -1.0f);            // tanh(c1)
    h1 = o1 * th1;

    float z2[4];
#pragma unroll
    for (int k = 0; k < 4; k++) {
        float z = s.b2[k];
        z = fmaf(a0, s.V2[k],      z);
        z = fmaf(a1, s.V2[4 + k],  z);
        z = fmaf(a2, s.V2[8 + k],  z);
        z = fmaf(a3, s.V2[12 + k], z);
        z = fmaf(h1, s.W2[k], z);
        z = fmaf(h2, s.U2[k], z);
        z2[k] = z;
    }
    float i2 = sigm(z2[0]);
    float f2 = sigm(z2[1]);
    float rg2 = sigm(z2[2]);
    float gp2 = fmaf(-4.0f * LOG2E, rg2, 2.0f * LOG2E);
    float o2 = sigm(z2[3]);
    C2 = fmaf(f2, C2, i2 * gp2);
    float th2 = fmaf(2.0f, sigm(C2), -1.0f);
    h2 = o2 * th2;
    return fmaf(h2, s.fw, s.fb);
}

// 8 steps from a 10x float4 register buffer; store 8 results if doStore.
__device__ __forceinline__ void compute8(
    const float4 (&buf)[10], const SW& s,
    float& h1, float& C1, float& h2, float& C2,
    float* op, bool doStore)
{
    float res[8];
#pragma unroll
    for (int j = 0; j < 8; j++) {
        res[j] = fstep(AV(buf, 5*j+0), AV(buf, 5*j+1), AV(buf, 5*j+2),
                       AV(buf, 5*j+3), AV(buf, 5*j+4), s, h1, C1, h2, C2);
    }
    if (doStore) {
        float4* o4 = (float4*)op;
        o4[0] = make_float4(res[0], res[1], res[2], res[3]);
        o4[1] = make_float4(res[4], res[5], res[6], res[7]);
    }
}

__global__ __launch_bounds__(256, 1) void pew_lstm_kernel(
    const float* __restrict__ input,
    const float* __restrict__ W1, const float* __restrict__ U1,
    const float* __restrict__ V1, const float* __restrict__ b1,
    const float* __restrict__ W2, const float* __restrict__ U2,
    const float* __restrict__ V2, const float* __restrict__ b2,
    const float* __restrict__ fcW, const float* __restrict__ fcb,
    float* __restrict__ out, int B)
{
    const int lane = threadIdx.x & 63;
    const int wv   = (blockIdx.x * blockDim.x + threadIdx.x) >> 6; // global wave
    const int chunk = wv & 7;                 // 8 time chunks per sequence
    const int seq   = ((wv >> 3) << 6) + lane;
    if (seq >= B) return;

    SW s;
#pragma unroll
    for (int k = 0; k < 4; k++) {
        const float sc = (k == 2) ? (-2.0f * LOG2E) : (-LOG2E);
        s.b1[k] = sc * b1[k]; s.W1[k] = sc * W1[k]; s.U1[k] = sc * U1[k];
        s.b2[k] = sc * b2[k]; s.W2[k] = sc * W2[k]; s.U2[k] = sc * U2[k];
#pragma unroll
        for (int j = 0; j < 4; j++) {
            s.V1[j*4 + k] = sc * V1[j*4 + k];
            s.V2[j*4 + k] = sc * V2[j*4 + k];
        }
    }
    s.fw = fcW[0]; s.fb = fcb[0];

    // chunk geometry: outputs [128*chunk, 128*chunk+128); warmup 64 (chunk 0: 0)
    const int t0   = (chunk << 7) - (chunk ? 64 : 0);
    const int nblk = chunk ? 24 : 16;          // 8-step blocks (even)
    const int kst  = chunk ? 8 : 0;            // first block that stores

    const float4* __restrict__ p =
        reinterpret_cast<const float4*>(input + (size_t)seq * 5120 + (size_t)t0 * 5);
    float* __restrict__ op = out + (size_t)seq * 1024 + t0;

    float4 bufA[10], bufB[10];
#pragma unroll
    for (int q = 0; q < 10; q++) bufA[q] = p[q];

    float h1 = 0.f, C1 = 0.f, h2 = 0.f, C2 = 0.f;

#pragma unroll 1
    for (int k = 0; k < nblk; k += 2) {
#pragma unroll
        for (int q = 0; q < 10; q++) bufB[q] = p[10 * (k + 1) + q];
        __builtin_amdgcn_sched_barrier(0);     // pin prefetch before compute
        compute8(bufA, s, h1, C1, h2, C2, op + 8 * k, k >= kst);
        if (k + 2 < nblk) {
#pragma unroll
            for (int q = 0; q < 10; q++) bufA[q] = p[10 * (k + 2) + q];
        }
        __builtin_amdgcn_sched_barrier(0);
        compute8(bufB, s, h1, C1, h2, C2, op + 8 * (k + 1), k + 1 >= kst);
    }
}

extern "C" void kernel_launch(void* const* d_in, const int* in_sizes, int n_in,
                              void* d_out, int out_size, void* d_ws, size_t ws_size,
                              hipStream_t stream) {
    const float* input = (const float*)d_in[0];
    const float* W1 = (const float*)d_in[1];
    const float* U1 = (const float*)d_in[2];
    const float* V1 = (const float*)d_in[3];
    const float* b1 = (const float*)d_in[4];
    const float* W2 = (const float*)d_in[5];
    const float* U2 = (const float*)d_in[6];
    const float* V2 = (const float*)d_in[7];
    const float* b2 = (const float*)d_in[8];
    const float* fcW = (const float*)d_in[9];
    const float* fcb = (const float*)d_in[10];
    float* out = (float*)d_out;

    int B = in_sizes[0] / (1024 * 5);
    // one thread per (seq, chunk): 8B threads total
    int blocks = (8 * B + 255) / 256;
    hipLaunchKernelGGL(pew_lstm_kernel, dim3(blocks), dim3(256), 0, stream,
                       input, W1, U1, V1, b1, W2, U2, V2, b2, fcW, fcb, out, B);
}